// Round 9
// baseline (119.884 us; speedup 1.0000x reference)
//
#include <hip/hip_runtime.h>
#include <hip/hip_bf16.h>
#include <stdint.h>

#define NB    4096
#define NROWS 8192
#define DIM   512
#define BM    128
#define NKT   4                       // K-tiles of 128 (MX-fp8 MFMA K)
#define NBLK  2176                    // 8 XCDs x 272 (96 early-exit)

typedef __attribute__((ext_vector_type(4))) float f32x4;
typedef __attribute__((ext_vector_type(8))) int   i32x8;

#define SCALE_E8M0 0x7B7B7B7Bu   // 2^-4 per 32-elem block, all blocks

// f32 -> OCP e4m3fn, RNE. Inputs |x| <= ~8 here (no sat needed).
__device__ __forceinline__ unsigned char f2e4m3(float x) {
  uint32_t u = __float_as_uint(x);
  uint32_t s = (u >> 24) & 0x80u;
  uint32_t e = (u >> 23) & 0xffu;
  if (e < 117u) return (unsigned char)s;          // < 2^-10 -> 0
  if (e >= 121u) {                                // normal fp8 range
    u += 0x7FFFFu + ((u >> 20) & 1u);             // RNE on mantissa bit 20
    e = (u >> 23) & 0xffu;
    uint32_t m = (u >> 20) & 7u;
    return (unsigned char)(s | ((e - 120u) << 3) | m);
  }
  float af = __uint_as_float(u & 0x7fffffffu);    // subnormal: step 2^-9
  int q = (int)(af * 512.0f + 0.5f);
  return (unsigned char)(q > 7 ? (s | 0x08u) : (s | (uint32_t)q));
}

// ---- Kernel 1: normalize rows -> fp8 P (v*16, e4m3), pos partials, zero ---
__global__ __launch_bounds__(256) void normalize_pos_kernel(
    const float* __restrict__ zi, const float* __restrict__ zj,
    unsigned char* __restrict__ p, float* __restrict__ rowsum,
    float* __restrict__ posp) {
  __shared__ float ws4[4];
  const int wave = threadIdx.x >> 6;
  const int lane = threadIdx.x & 63;
  const int i    = blockIdx.x * 4 + wave;          // 0..4095

  int gt = blockIdx.x * 256 + threadIdx.x;
  if (gt < NROWS) rowsum[gt] = 0.f;

  const float4* sa = (const float4*)(zi + (size_t)i * DIM);
  const float4* sb = (const float4*)(zj + (size_t)i * DIM);
  float4 a0 = sa[lane * 2], a1 = sa[lane * 2 + 1];
  float4 b0 = sb[lane * 2], b1 = sb[lane * 2 + 1];
  float va[8] = {a0.x, a0.y, a0.z, a0.w, a1.x, a1.y, a1.z, a1.w};
  float vb[8] = {b0.x, b0.y, b0.z, b0.w, b1.x, b1.y, b1.z, b1.w};
  float ssa = 0.f, ssb = 0.f;
#pragma unroll
  for (int j = 0; j < 8; ++j) { ssa += va[j] * va[j]; ssb += vb[j] * vb[j]; }
#pragma unroll
  for (int off = 32; off; off >>= 1) {
    ssa += __shfl_xor(ssa, off);
    ssb += __shfl_xor(ssb, off);
  }
  float inva = rsqrtf(ssa), invb = rsqrtf(ssb);

  union { unsigned char b[8]; uint2 v; } qa, qb;
  float d = 0.f;
#pragma unroll
  for (int j = 0; j < 8; ++j) {
    float na = va[j] * inva, nb = vb[j] * invb;
    qa.b[j] = f2e4m3(na * 16.0f);
    qb.b[j] = f2e4m3(nb * 16.0f);
    d += na * nb;
  }
  *(uint2*)(p + (size_t)i * DIM + lane * 8)        = qa.v;
  *(uint2*)(p + (size_t)(i + NB) * DIM + lane * 8) = qb.v;

#pragma unroll
  for (int off = 32; off; off >>= 1) d += __shfl_xor(d, off);
  if (lane == 0) ws4[wave] = d;
  __syncthreads();
  if (threadIdx.x == 0)
    posp[blockIdx.x] = 4.0f * (ws4[0] + ws4[1] + ws4[2] + ws4[3]);
}

// ---- Kernel 2: symmetric fused S = 2*P*P^T (MX-fp8) -> exp -> row+col sums
// NO LDS, NO barriers: P is L1/L2-resident (4 MB total, 32 KB per K-slice),
// so MFMA fragments load straight global->VGPR (layout verified by R8:
// lane=(frow,kc) reads 32 contiguous bytes at row*512 + kt*128 + kc*32).
// Supertile XCD map kept for L2 locality.
__global__ __launch_bounds__(256, 2) void simexp_kernel(
    const unsigned char* __restrict__ p, float* __restrict__ rowsum) {
  const int x = blockIdx.x & 7;          // XCD (round-robin heuristic)
  const int l = blockIdx.x >> 3;         // 0..271 local index
  int bi, bj;
  if (x < 6) {
    if (l >= 256) return;
    const int sqi[6] = {0, 0, 0, 1, 1, 2};
    const int sqj[6] = {1, 2, 3, 2, 3, 3};
    bi = sqi[x] * 16 + (l >> 4);
    bj = sqj[x] * 16 + (l & 15);
  } else {
    int s  = (x == 6) ? 0 : 2;
    int ll = l;
    if (ll >= 136) { ll -= 136; s += 1; }
    int i = 0;
    while ((i + 1) * (33 - (i + 1)) / 2 <= ll) ++i;
    int j = i + (ll - i * (33 - i) / 2);
    bi = s * 16 + i;
    bj = s * 16 + j;
  }
  const bool diag = (bi == bj);

  const int tid  = threadIdx.x;
  const int wave = tid >> 6;
  const int lane = tid & 63;
  const int wm   = wave >> 1;
  const int wn   = wave & 1;
  const int frow = lane & 15;
  const int kc   = lane >> 4;      // 0..3 : 32-elem k-block

  // per-lane fragment base pointers (8 total); K-tile advances via imm offset
  const char* pa[4];
  const char* pb[4];
#pragma unroll
  for (int m = 0; m < 4; ++m)
    pa[m] = (const char*)p +
            (size_t)(bi * BM + wm * 64 + m * 16 + frow) * DIM + kc * 32;
#pragma unroll
  for (int n = 0; n < 4; ++n)
    pb[n] = (const char*)p +
            (size_t)(bj * BM + wn * 64 + n * 16 + frow) * DIM + kc * 32;

  f32x4 acc[4][4] = {};

#pragma unroll
  for (int t = 0; t < NKT; ++t) {
    i32x8 af[4], bfr[4];
#pragma unroll
    for (int m = 0; m < 4; ++m) af[m] = *(const i32x8*)(pa[m] + t * 128);
#pragma unroll
    for (int n = 0; n < 4; ++n) bfr[n] = *(const i32x8*)(pb[n] + t * 128);
#pragma unroll
    for (int m = 0; m < 4; ++m)
#pragma unroll
      for (int n = 0; n < 4; ++n)
        acc[m][n] = __builtin_amdgcn_mfma_scale_f32_16x16x128_f8f6f4(
            af[m], bfr[n], acc[m][n],
            0 /*cbsz: fp8*/, 0 /*blgp: fp8*/,
            0, SCALE_E8M0, 0, SCALE_E8M0);
  }

  // epilogue: e = exp(2s); rowsum[row] += e; rowsum[col] += e if off-diag
  const int r4 = lane >> 4;   // C/D: col = lane&15, row = (lane>>4)*4 + reg
  const int cl = lane & 15;

  float rowpart[4][4];
  float colpart[4] = {0.f, 0.f, 0.f, 0.f};

  if (diag) {
#pragma unroll
    for (int m = 0; m < 4; ++m)
#pragma unroll
      for (int r = 0; r < 4; ++r) {
        int grow = bi * BM + wm * 64 + m * 16 + r4 * 4 + r;
        float s = 0.f;
#pragma unroll
        for (int n = 0; n < 4; ++n) {
          int gcol = bj * BM + wn * 64 + n * 16 + cl;
          float e  = __expf(2.0f * acc[m][n][r]);
          s += (grow == gcol) ? 0.f : e;
        }
        rowpart[m][r] = s;
      }
  } else {
#pragma unroll
    for (int m = 0; m < 4; ++m)
#pragma unroll
      for (int r = 0; r < 4; ++r) {
        float s = 0.f;
#pragma unroll
        for (int n = 0; n < 4; ++n) {
          float e = __expf(2.0f * acc[m][n][r]);
          s += e;
          colpart[n] += e;
        }
        rowpart[m][r] = s;
      }
  }

#pragma unroll
  for (int m = 0; m < 4; ++m)
#pragma unroll
    for (int r = 0; r < 4; ++r) {
      float s = rowpart[m][r];
      s += __shfl_xor(s, 1);
      s += __shfl_xor(s, 2);
      s += __shfl_xor(s, 4);
      s += __shfl_xor(s, 8);
      if (cl == 0) {
        int grow = bi * BM + wm * 64 + m * 16 + r4 * 4 + r;
        atomicAdd(&rowsum[grow], s);
      }
    }

  if (!diag) {
#pragma unroll
    for (int n = 0; n < 4; ++n) {
      float c = colpart[n];
      c += __shfl_xor(c, 16);
      c += __shfl_xor(c, 32);
      if (r4 == 0) {
        int gcol = bj * BM + wn * 64 + n * 16 + cl;
        atomicAdd(&rowsum[gcol], c);
      }
    }
  }
}

// ---- Kernel 3: finalize loss ---------------------------------------------
__global__ __launch_bounds__(256) void finalize_kernel(
    const float* __restrict__ rowsum, const float* __restrict__ posp,
    float* __restrict__ out) {
  __shared__ float ws4[4];
  int tid = threadIdx.x;
  float v = 0.f;
  for (int i = tid; i < NROWS; i += 256) v += logf(rowsum[i]);
  for (int i = tid; i < 1024; i += 256) v -= posp[i];
#pragma unroll
  for (int off = 32; off; off >>= 1) v += __shfl_xor(v, off);
  if ((tid & 63) == 0) ws4[tid >> 6] = v;
  __syncthreads();
  if (tid == 0)
    out[0] = (ws4[0] + ws4[1] + ws4[2] + ws4[3]) / (float)NROWS;
}

extern "C" void kernel_launch(void* const* d_in, const int* in_sizes, int n_in,
                              void* d_out, int out_size, void* d_ws,
                              size_t ws_size, hipStream_t stream) {
  const float* zi = (const float*)d_in[0];
  const float* zj = (const float*)d_in[1];
  float* out      = (float*)d_out;

  char* ws          = (char*)d_ws;
  unsigned char* p  = (unsigned char*)ws;                        // 4 MB fp8
  float* rowsum     = (float*)(ws + (size_t)NROWS * DIM);        // 32 KB
  float* posp       = rowsum + NROWS;                            // 4 KB

  normalize_pos_kernel<<<NB / 4, 256, 0, stream>>>(zi, zj, p, rowsum, posp);
  simexp_kernel<<<NBLK, 256, 0, stream>>>(p, rowsum);
  finalize_kernel<<<1, 256, 0, stream>>>(rowsum, posp, out);
}